// Round 3
// baseline (3911.931 us; speedup 1.0000x reference)
//
#include <hip/hip_runtime.h>
#include <math.h>

#define MTOT 32768   // B*R
#define DD   512
#define HHD  1024
#define NRELN 2048
#define SCA  64.f          // activation fp16 pre-scale
#define SCB  1024.f        // weight fp16 pre-scale
#define INVS (1.f / 65536.f)
#define CAPR 4096          // rescue row capacity (expected ~1300/step)
#define MARGIN 2.0e-3f     // approx-gap rescue threshold (~50 sigma of approx err)

typedef _Float16 h8  __attribute__((ext_vector_type(8)));
typedef float    f4  __attribute__((ext_vector_type(4)));
typedef float    f16v __attribute__((ext_vector_type(16)));

__device__ __forceinline__ void fsplit(float x, _Float16& h, _Float16& l) {
  _Float16 t = (_Float16)x;
  h = t;
  l = (_Float16)(x - (float)t);   // hi/lo split: 2^-22 rel error total
}

__device__ __forceinline__ void gld16(const _Float16* g, _Float16* l) {
  __builtin_amdgcn_global_load_lds(
      (const __attribute__((address_space(1))) void*)g,
      (__attribute__((address_space(3))) void*)l, 16, 0, 0);
}

// ---------------- prep: fold + scale + split weights ----------------

__global__ void prep_wvo_split(const float* __restrict__ vw, const float* __restrict__ ow,
                               _Float16* __restrict__ wh, _Float16* __restrict__ wl) {
  int idx = blockIdx.x * 256 + threadIdx.x;   // 512*512
  int k = idx & 511;
  int n = idx >> 9;
  float s = 0.f;
  for (int j = 0; j < DD; ++j) s += ow[n * DD + j] * vw[j * DD + k];
  fsplit(s * SCB, wh[n * DD + k], wl[n * DD + k]);
}

__global__ void prep_cvec(const float* __restrict__ ow, const float* __restrict__ vb,
                          const float* __restrict__ ob, float* __restrict__ c) {
  int i = blockIdx.x * 256 + threadIdx.x;
  if (i < DD) {
    float s = ob[i];
    for (int k = 0; k < DD; ++k) s += ow[i * DD + k] * vb[k];
    c[i] = s;
  }
}

__global__ void prep_w1p_split(const float* __restrict__ w1, const float* __restrict__ g,
                               _Float16* __restrict__ wh, _Float16* __restrict__ wl) {
  int idx = blockIdx.x * 256 + threadIdx.x;   // 1024*512
  int k = idx & 511;
  int n = idx >> 9;
  fsplit(w1[n * DD + k] * g[k] * SCB, wh[n * DD + k], wl[n * DD + k]);
}

__global__ void prep_b1p(const float* __restrict__ w1, const float* __restrict__ lnb,
                         const float* __restrict__ b1, float* __restrict__ b1p) {
  int n = blockIdx.x * 256 + threadIdx.x;
  if (n < HHD) {
    float s = b1[n];
    for (int k = 0; k < DD; ++k) s += w1[n * DD + k] * lnb[k];
    b1p[n] = s;
  }
}

__global__ void prep_w2_split(const float* __restrict__ w2,
                              _Float16* __restrict__ wh, _Float16* __restrict__ wl) {
  int idx = blockIdx.x * 256 + threadIdx.x;   // 2048*1024
  int k = idx & 1023;
  int n = idx >> 10;
  fsplit(w2[n * HHD + k] * SCB, wh[n * HHD + k], wl[n * HHD + k]);
}

__global__ void split_x(const float* __restrict__ src, _Float16* __restrict__ h,
                        _Float16* __restrict__ l) {
  int idx = (blockIdx.x * 256 + threadIdx.x) * 8;
  float4 a = *(const float4*)(src + idx);
  float4 b = *(const float4*)(src + idx + 4);
  float vv[8] = {a.x, a.y, a.z, a.w, b.x, b.y, b.z, b.w};
  _Float16 hh[8], ll[8];
#pragma unroll
  for (int i = 0; i < 8; ++i) fsplit(vv[i] * SCA, hh[i], ll[i]);
  *(h8*)(h + idx) = *(h8*)hh;
  *(h8*)(l + idx) = *(h8*)ll;
}

__global__ void zero_cnt(int* c) { c[blockIdx.x * 256 + threadIdx.x] = 0; }

// ---------------- exact fp16-split GEMM (3-product), 128x128, BK=32 ----------
// SW(r) = ((r>>1)^(r>>3))&3 chunk swizzle.
// MODE 0: +bias -> fp32 out. MODE 1: +bias, relu, *SCA, split -> H.
// MODE 2: rescue rows (count from *cntp, grid-stride): per-row (max, argmax)
//         -> pM/pI partials (32 col-slots), stride pstr.
template <int MODE, int KDIM, int NTOT>
__global__ __launch_bounds__(256) void gemm_split(
    const _Float16* __restrict__ Ah, const _Float16* __restrict__ Al,
    const _Float16* __restrict__ Bh, const _Float16* __restrict__ Bl,
    const float* __restrict__ bias,
    float* __restrict__ outF,
    _Float16* __restrict__ outHh, _Float16* __restrict__ outHl,
    float* __restrict__ pM, float* __restrict__ pI,
    const int* __restrict__ cntp, int pstr) {
  __shared__ __align__(16) _Float16 sA[2][128][32];
  __shared__ __align__(16) _Float16 sB[2][128][32];
  const int t = threadIdx.x;
  const int lane = t & 63;
  const int wv = t >> 6;
  const int wr = wv & 1, wc = wv >> 1;
  const int l31 = lane & 31, half = lane >> 5;
  const int n0 = blockIdx.y << 7;

  const _Float16* gsp = (wv == 0) ? Ah : (wv == 1) ? Al : (wv == 2) ? Bh : Bl;
  _Float16* lbase = (wv == 0) ? &sA[0][0][0] : (wv == 1) ? &sA[1][0][0]
                  : (wv == 2) ? &sB[0][0][0] : &sB[1][0][0];
  const int srow = lane >> 2;
  const int scp = lane & 3;
  const int swzE = ((srow >> 1) & 3) ^ ((srow >> 3) & 1);
  const int swzO = swzE ^ 2;
  const int swz = ((l31 >> 1) ^ (l31 >> 3)) & 3;   // frag-read side

  int nmb;
  if constexpr (MODE == 2) {
    int a = *cntp;
    if (a > CAPR) a = CAPR;
    nmb = (a + 127) >> 7;
  } else {
    nmb = gridDim.x;
  }

  for (int mb = blockIdx.x; mb < nmb; mb += gridDim.x) {
    const int m0 = mb << 7;
    const int gb = (wv < 2) ? m0 : n0;
    const _Float16* gA0 = gsp + (size_t)(gb + srow) * KDIM + ((scp ^ swzE) << 3);
    const _Float16* gA1 = gsp + (size_t)(gb + srow) * KDIM + ((scp ^ swzO) << 3);

    f16v acc[2][2] = {};
    for (int k0 = 0; k0 < KDIM; k0 += 32) {
      __syncthreads();
#pragma unroll
      for (int it = 0; it < 8; ++it)
        gld16(((it & 1) ? gA1 : gA0) + (size_t)(it * 16) * KDIM + k0, lbase + it * 512);
      __syncthreads();
#pragma unroll
      for (int ks = 0; ks < 2; ++ks) {
        const int pos = (((ks << 1) + half) ^ swz) << 3;
        h8 af_h[2], af_l[2], bf_h[2], bf_l[2];
#pragma unroll
        for (int i = 0; i < 2; ++i) {
          const int mr = wr * 64 + i * 32 + l31;
          af_h[i] = *(const h8*)&sA[0][mr][pos];
          af_l[i] = *(const h8*)&sA[1][mr][pos];
        }
#pragma unroll
        for (int j = 0; j < 2; ++j) {
          const int nr = wc * 64 + j * 32 + l31;
          bf_h[j] = *(const h8*)&sB[0][nr][pos];
          bf_l[j] = *(const h8*)&sB[1][nr][pos];
        }
#pragma unroll
        for (int j = 0; j < 2; ++j)
#pragma unroll
          for (int i = 0; i < 2; ++i) {
            acc[i][j] = __builtin_amdgcn_mfma_f32_32x32x16_f16(af_h[i], bf_h[j], acc[i][j], 0, 0, 0);
            acc[i][j] = __builtin_amdgcn_mfma_f32_32x32x16_f16(af_h[i], bf_l[j], acc[i][j], 0, 0, 0);
            acc[i][j] = __builtin_amdgcn_mfma_f32_32x32x16_f16(af_l[i], bf_h[j], acc[i][j], 0, 0, 0);
          }
      }
    }

    // C/D (32x32): col = lane&31, row = (r&3)+8*(r>>2)+4*half
    float bb[2];
    int gc[2];
#pragma unroll
    for (int j = 0; j < 2; ++j) {
      gc[j] = n0 + wc * 64 + j * 32 + l31;
      bb[j] = bias[gc[j]];
    }
    if constexpr (MODE == 0) {
#pragma unroll
      for (int i = 0; i < 2; ++i)
#pragma unroll
        for (int r = 0; r < 16; ++r) {
          const int row = m0 + wr * 64 + i * 32 + (r & 3) + 8 * (r >> 2) + 4 * half;
#pragma unroll
          for (int j = 0; j < 2; ++j)
            outF[(size_t)row * NTOT + gc[j]] = acc[i][j][r] * INVS + bb[j];
        }
    } else if constexpr (MODE == 1) {
#pragma unroll
      for (int i = 0; i < 2; ++i)
#pragma unroll
        for (int r = 0; r < 16; ++r) {
          const int row = m0 + wr * 64 + i * 32 + (r & 3) + 8 * (r >> 2) + 4 * half;
#pragma unroll
          for (int j = 0; j < 2; ++j) {
            float v = fmaxf(acc[i][j][r] * INVS + bb[j], 0.f) * SCA;
            _Float16 hh, ll;
            fsplit(v, hh, ll);
            outHh[(size_t)row * NTOT + gc[j]] = hh;
            outHl[(size_t)row * NTOT + gc[j]] = ll;
          }
        }
    } else {
      const int slot = blockIdx.y * 2 + wc;   // 32 col-slots of 64
#pragma unroll
      for (int i = 0; i < 2; ++i)
#pragma unroll
        for (int r = 0; r < 16; ++r) {
          float v0 = acc[i][0][r] * INVS + bb[0];
          float v1 = acc[i][1][r] * INVS + bb[1];
          float M;
          int I;
          if (v0 >= v1) { M = v0; I = gc[0]; }
          else          { M = v1; I = gc[1]; }
#pragma unroll
          for (int sh = 1; sh <= 16; sh <<= 1) {
            float M2 = __shfl_xor(M, sh);
            int   I2 = __shfl_xor(I, sh);
            if (M2 > M || (M2 == M && I2 < I)) { M = M2; I = I2; }
          }
          if (l31 == 0) {
            const int grow = m0 + wr * 64 + i * 32 + (r & 3) + 8 * (r >> 2) + 4 * half;
            pM[(size_t)slot * pstr + grow] = M;
            pI[(size_t)slot * pstr + grow] = (float)I;
          }
        }
    }
  }
}

// ---------------- approx GEMM (hh only): 256x256, BK=64, single-buffer ------
// Round-3 restructure for cross-block latency hiding (m114): the 8-phase
// 128-KiB kernel allowed only 1 block/CU (2 waves/SIMD, all barrier-locked)
// -> every vmcnt/barrier stall left the matrix pipe empty (MfmaUtil 21%,
// dur identical to the round-0 schedule; memory traffic already minimal
// after the XCD decode -> latency-bound, not BW/conflict/schedule-bound).
// Now: ONE 64-KiB buffer (A[256][64] | B[256][64]), per K-tile:
//   __syncthreads -> 8x gld16 -> __syncthreads (compiler emits vmcnt(0)
//   drain before s_barrier) -> 64 MFMA/wave (compiler-scheduled).
// 64 KiB LDS -> 2 blocks/CU, 16 waves/CU, 4 waves/SIMD; all 512 blocks
// resident (zero tail). Block A's stage-drain overlaps block B's MFMA burst.
// Accumulation order per acc element identical to rounds 0-2 (same tile
// order, kc0 then kc1, same j-loop) -> bit-identical partials.
// XCD-aware (mb, nb) decode kept from round 2 (FETCH 180->80 MB).
// LDS k-chunk swizzle kept: chunk ^= row&7 via pre-swizzled global source
// (linear gld16 dest) + same XOR on ds_read -> 0 bank conflicts (measured).
// Epilogue: per-row online (max, 2nd-max, first-argmax, sumexp) -> 32
// col-slots of 64, stride astr (chunk-local rows).

__global__ __launch_bounds__(512, 4) void gemm_approx(
    const _Float16* __restrict__ Ah, const _Float16* __restrict__ Bh,
    const float* __restrict__ bias,
    float* __restrict__ pM, float* __restrict__ pM2,
    float* __restrict__ pS, int* __restrict__ pI, int astr) {
  __shared__ __align__(16) _Float16 lds[32768];   // A[256][64] | B[256][64]
  const int t = threadIdx.x;
  const int lane = t & 63;
  const int wv = t >> 6;        // 0..7
  const int wr = wv >> 2;       // m half (0..1)
  const int wc = wv & 3;        // n quarter (0..3)
  const int q = lane >> 4;      // 0..3
  const int l16 = lane & 15;
  const int s7 = l16 & 7;
  const int l8 = lane >> 3;     // staging: row-in-chunk 0..7
  const int lc = lane & 7;      // staging: chunk-pos 0..7

  // ---- XCD-aware (mb, nb) decode (round 2) ----
  // Groups of 64 linear ids = 8 m-strips x 8 n-tiles; all 8 n-tiles of a
  // strip get ids congruent mod 8 -> same XCD. Partial last group bijective.
  const int Yg = gridDim.y;
  const int id = blockIdx.x + (blockIdx.y << 3);
  const int g8 = (id >> 6) << 3;
  const int r = id & 63;
  int mb, nb;
  if (g8 + 8 <= Yg) { mb = g8 + (r & 7); nb = r >> 3; }
  else { int rem = Yg - g8; mb = g8 + (r % rem); nb = r / rem; }

  const int m0 = mb << 8;
  const int n0 = nb << 8;

  // staging bases (global half-offsets at kt=0; LDS half-offsets)
  const int swz8 = (lc ^ l8) << 3;   // inverse-swizzled source k-chunk
  const int sBb = (n0 + wc * 64 + wr * 8 + l8) * HHD + swz8;
  const int dBb = (wc * 64 + wr * 8) * 64;
  const int sAb = (m0 + wr * 128 + wc * 8 + l8) * HHD + swz8;
  const int dAb = (wr * 128 + wc * 8) * 64;

  // frag-read constants (swizzled k-chunks for the two 32-k steps)
  const int kc0 = ((q) ^ s7) << 3;
  const int kc1 = ((q + 4) ^ s7) << 3;
  const int aRow = (wr * 128 + l16) * 64;
  const int bRow = 16384 + (wc * 64 + l16) * 64;

  f4 acc[8][4] = {};

  for (int kt = 0; kt < 16; ++kt) {
    __syncthreads();   // all waves done reading the buffer (no-op at kt=0)
#pragma unroll
    for (int k = 0; k < 4; ++k) {
      gld16(Bh + (size_t)(sBb + k * 16384 + kt * 64), lds + 16384 + dBb + k * 1024);
      gld16(Ah + (size_t)(sAb + k * 32768 + kt * 64), lds + dAb + k * 2048);
    }
    __syncthreads();   // vmcnt(0) drain + barrier: all 128 KB-tile loads landed
    __builtin_amdgcn_s_setprio(1);
    h8 bf0[4], bf1[4];
#pragma unroll
    for (int j = 0; j < 4; ++j) {
      bf0[j] = *(const h8*)(lds + bRow + j * 1024 + kc0);
      bf1[j] = *(const h8*)(lds + bRow + j * 1024 + kc1);
    }
#pragma unroll
    for (int p = 0; p < 4; ++p) {
      h8 a00 = *(const h8*)(lds + aRow + (2 * p) * 1024 + kc0);
      h8 a01 = *(const h8*)(lds + aRow + (2 * p) * 1024 + kc1);
      h8 a10 = *(const h8*)(lds + aRow + (2 * p + 1) * 1024 + kc0);
      h8 a11 = *(const h8*)(lds + aRow + (2 * p + 1) * 1024 + kc1);
#pragma unroll
      for (int j = 0; j < 4; ++j) {
        acc[2 * p][j] = __builtin_amdgcn_mfma_f32_16x16x32_f16(a00, bf0[j], acc[2 * p][j], 0, 0, 0);
        acc[2 * p][j] = __builtin_amdgcn_mfma_f32_16x16x32_f16(a01, bf1[j], acc[2 * p][j], 0, 0, 0);
        acc[2 * p + 1][j] = __builtin_amdgcn_mfma_f32_16x16x32_f16(a10, bf0[j], acc[2 * p + 1][j], 0, 0, 0);
        acc[2 * p + 1][j] = __builtin_amdgcn_mfma_f32_16x16x32_f16(a11, bf1[j], acc[2 * p + 1][j], 0, 0, 0);
      }
    }
    __builtin_amdgcn_s_setprio(0);
  }

  // epilogue; C/D 16x16: row = q*4+rr, col = l16 (verified layout)
  const int slot = nb * 4 + wc;   // 32 slots of 64 cols
  float bb[4];
  int gcx[4];
#pragma unroll
  for (int j = 0; j < 4; ++j) {
    gcx[j] = n0 + wc * 64 + j * 16 + l16;
    bb[j] = bias[gcx[j]];
  }
#pragma unroll
  for (int i = 0; i < 8; ++i)
#pragma unroll
    for (int rr = 0; rr < 4; ++rr) {
      float M = acc[i][0][rr] * INVS + bb[0], M2 = -INFINITY, S = 1.f;
      int I = gcx[0];
#pragma unroll
      for (int j = 1; j < 4; ++j) {
        float v = acc[i][j][rr] * INVS + bb[j];
        if (v > M || (v == M && gcx[j] < I)) {
          S = S * __expf(M - v) + 1.f; M2 = M; M = v; I = gcx[j];
        } else {
          S += __expf(v - M); M2 = fmaxf(M2, v);
        }
      }
#pragma unroll
      for (int sh = 1; sh <= 8; sh <<= 1) {   // reduce across the 16-lane group
        float Mo = __shfl_xor(M, sh);
        float M2o = __shfl_xor(M2, sh);
        float So = __shfl_xor(S, sh);
        int   Io = __shfl_xor(I, sh);
        if (Mo > M || (Mo == M && Io < I)) {
          S = S * __expf(M - Mo) + So; M2 = fmaxf(M, M2o); M = Mo; I = Io;
        } else {
          S += So * __expf(Mo - M); M2 = fmaxf(M2, Mo);
        }
      }
      if (l16 == 0) {
        const int grow = m0 + wr * 128 + i * 16 + q * 4 + rr;
        pM[(size_t)slot * astr + grow] = M;
        pM2[(size_t)slot * astr + grow] = M2;
        pS[(size_t)slot * astr + grow] = S;
        pI[(size_t)slot * astr + grow] = I;
      }
    }
}

// -------- flag: merge 32 approx slots; emit m/i; flag small gaps ----
__global__ void flag_k(const float* __restrict__ pM, const float* __restrict__ pM2,
                       const float* __restrict__ pS, const int* __restrict__ pI,
                       int astr, int rows,
                       float* __restrict__ map, int* __restrict__ iap, int row0,
                       int* __restrict__ list, int* __restrict__ cnt) {
  int r = blockIdx.x * 256 + threadIdx.x;
  if (r >= rows) return;
  float M = pM[r], M2 = pM2[r], S = pS[r];
  int I = pI[r];
  for (int s = 1; s < 32; ++s) {
    size_t o = (size_t)s * astr + r;
    float m = pM[o], m2 = pM2[o], ss = pS[o];
    int ii = pI[o];
    if (m > M || (m == M && ii < I)) {
      M2 = fmaxf(M, m2); S = S * __expf(M - m) + ss; M = m; I = ii;
    } else {
      M2 = fmaxf(M2, m); S += ss * __expf(m - M);
    }
  }
  map[row0 + r] = 1.f / S;
  iap[row0 + r] = I;
  if (M - M2 < MARGIN) {
    int c = atomicAdd(cnt, 1);
    if (c < CAPR) list[c] = r;   // chunk-local row
  }
}

// -------- gather flagged H rows (exact split) into dense rescue buffer ------
__global__ void gather_k(const _Float16* __restrict__ Hh, const _Float16* __restrict__ Hl,
                         const int* __restrict__ list, const int* __restrict__ cnt,
                         _Float16* __restrict__ Gh, _Float16* __restrict__ Gl) {
  int b = blockIdx.x;
  int active = *cnt;
  if (active > CAPR) active = CAPR;
  if (b >= active) return;
  int r = list[b];
  int t = threadIdx.x;   // 128 threads x 8 halfs = 1024
  *(h8*)(Gh + (size_t)b * HHD + t * 8) = *(const h8*)(Hh + (size_t)r * HHD + t * 8);
  *(h8*)(Gl + (size_t)b * HHD + t * 8) = *(const h8*)(Hl + (size_t)r * HHD + t * 8);
}

// -------- rescue merge: exact argmax over 32 slots -> overwrite iap ---------
__global__ void rescue_merge(const float* __restrict__ pMr, const float* __restrict__ pIr,
                             const int* __restrict__ list, const int* __restrict__ cnt,
                             int* __restrict__ iap, int row0) {
  int c = blockIdx.x * 256 + threadIdx.x;
  int a = *cnt;
  if (a > CAPR) a = CAPR;
  if (c >= a) return;
  float M = pMr[c];
  int I = (int)pIr[c];
  for (int s = 1; s < 32; ++s) {
    size_t o = (size_t)s * CAPR + c;
    float m = pMr[o];
    int i2 = (int)pIr[o];
    if (m > M || (m == M && i2 < I)) { M = m; I = i2; }
  }
  iap[row0 + list[c]] = I;
}

// ------- ln_dual: one pass over A+X -> both step activations, split --------
__global__ __launch_bounds__(256) void ln_dual(
    const float* __restrict__ A, const float* __restrict__ X,
    const float* __restrict__ na,
    _Float16* __restrict__ y0h, _Float16* __restrict__ y0l,
    _Float16* __restrict__ y1h, _Float16* __restrict__ y1l) {
  int t = threadIdx.x;
  int lane = t & 63;
  int w = t >> 6;
  int r = blockIdx.x * 4 + w;
  const float* ap = A + (size_t)r * DD + lane * 8;
  const float* xp = X + (size_t)r * DD + lane * 8;
  const float* np = na + lane * 8;
  float v0[8], v1[8];
  float s0 = 0.f, q0 = 0.f, s1 = 0.f, q1 = 0.f;
#pragma unroll
  for (int i = 0; i < 8; ++i) {
    float a = ap[i];
    v0[i] = a + np[i];
    v1[i] = a + xp[i];
    s0 += v0[i]; q0 += v0[i] * v0[i];
    s1 += v1[i]; q1 += v1[i] * v1[i];
  }
#pragma unroll
  for (int m = 1; m <= 32; m <<= 1) {
    s0 += __shfl_xor(s0, m); q0 += __shfl_xor(q0, m);
    s1 += __shfl_xor(s1, m); q1 += __shfl_xor(q1, m);
  }
  float mu0 = s0 * (1.f / DD), mu1 = s1 * (1.f / DD);
  float rs0 = 1.f / sqrtf(q0 * (1.f / DD) - mu0 * mu0 + 1e-5f);
  float rs1 = 1.f / sqrtf(q1 * (1.f / DD) - mu1 * mu1 + 1e-5f);
  _Float16 h0[8], l0[8], h1[8], l1[8];
#pragma unroll
  for (int i = 0; i < 8; ++i) {
    fsplit((v0[i] - mu0) * rs0 * SCA, h0[i], l0[i]);
    fsplit((v1[i] - mu1) * rs1 * SCA, h1[i], l1[i]);
  }
  *(h8*)(y0h + (size_t)r * DD + lane * 8) = *(h8*)h0;
  *(h8*)(y0l + (size_t)r * DD + lane * 8) = *(h8*)l0;
  *(h8*)(y1h + (size_t)r * DD + lane * 8) = *(h8*)h1;
  *(h8*)(y1l + (size_t)r * DD + lane * 8) = *(h8*)l1;
}

// ---------------- finalize ----------------
__global__ void finalize_k(const float* __restrict__ map0, const int* __restrict__ iap0,
                           const float* __restrict__ map1, const int* __restrict__ iap1,
                           float* __restrict__ out) {
  int r = blockIdx.x * 256 + threadIdx.x;
  float m0v = map0[r], m1v = map1[r];
  int i0v = iap0[r], i1v = iap1[r];
  bool c0 = (i0v != 0) && (m0v >= 0.1f);
  bool c1 = c0 && (i1v != 0) && (m1v >= 0.1f);
  out[r] = c0 ? (c1 ? m0v * m1v : m0v) : 0.f;
  out[MTOT + r] = (float)i0v;
  out[2 * MTOT + r] = (float)i1v;
  out[3 * MTOT + r] = (float)((c0 ? 1 : 0) + (c1 ? 1 : 0));
}

// ---------------- host ----------------
extern "C" void kernel_launch(void* const* d_in, const int* in_sizes, int n_in,
                              void* d_out, int out_size, void* d_ws, size_t ws_size,
                              hipStream_t stream) {
  const float* X   = (const float*)d_in[0];
  const float* na  = (const float*)d_in[1];
  const float* vw  = (const float*)d_in[2];
  const float* vb  = (const float*)d_in[3];
  const float* ow  = (const float*)d_in[4];
  const float* ob  = (const float*)d_in[5];
  const float* lng = (const float*)d_in[6];
  const float* lnb = (const float*)d_in[7];
  const float* w1  = (const float*)d_in[8];
  const float* b1  = (const float*)d_in[9];
  const float* w2  = (const float*)d_in[10];
  const float* b2  = (const float*)d_in[11];
  float* out = (float*)d_out;

  char* p = (char*)d_ws;
  auto alloc = [&](size_t bytes) -> void* {
    void* r = (void*)p;
    p += (bytes + 255) & ~(size_t)255;
    return r;
  };
  // ---- fixed allocations (~30 MB) ----
  _Float16* wvo_h = (_Float16*)alloc(512 * 512 * 2);
  _Float16* wvo_l = (_Float16*)alloc(512 * 512 * 2);
  float*    cvec  = (float*)alloc(512 * 4);
  _Float16* w1p_h = (_Float16*)alloc(1024 * 512 * 2);
  _Float16* w1p_l = (_Float16*)alloc(1024 * 512 * 2);
  float*    b1p   = (float*)alloc(1024 * 4);
  _Float16* w2_h  = (_Float16*)alloc(2048 * 1024 * 2);
  _Float16* w2_l  = (_Float16*)alloc(2048 * 1024 * 2);
  float* map0 = (float*)alloc((size_t)MTOT * 4);
  float* map1 = (float*)alloc((size_t)MTOT * 4);
  int* iap0 = (int*)alloc((size_t)MTOT * 4);
  int* iap1 = (int*)alloc((size_t)MTOT * 4);
  int* list = (int*)alloc(CAPR * 4);
  int* cnt  = (int*)alloc(512 * 4);   // per-(chunk,step) counters
  float* pMr = (float*)alloc((size_t)32 * CAPR * 4);
  float* pIr = (float*)alloc((size_t)32 * CAPR * 4);
  _Float16* Gh = (_Float16*)alloc((size_t)CAPR * HHD * 2);
  _Float16* Gl = (_Float16*)alloc((size_t)CAPR * HHD * 2);

  // ---- chunk sizing: per-row bytes = xs 2048 + A 2048 + y0 2048 + H 4096
  //      + approx partials (32 slots x 16 B) 512 = 10752 ----
  size_t fixed = (size_t)(p - (char*)d_ws);
  size_t reserve = 2u << 20;
  size_t remain = ws_size > fixed + reserve ? ws_size - fixed - reserve : 0;
  int chunk = (int)(remain / 10752);
  chunk &= ~255;                       // gemm_approx tiles 256 rows
  if (chunk < 256) chunk = 256;
  if (chunk > MTOT) chunk = MTOT;

  _Float16* xs_h = (_Float16*)alloc((size_t)chunk * 512 * 2);
  _Float16* xs_l = (_Float16*)alloc((size_t)chunk * 512 * 2);
  float*    Abuf = (float*)alloc((size_t)chunk * 512 * 4);
  _Float16* y0_h = (_Float16*)alloc((size_t)chunk * 512 * 2);
  _Float16* y0_l = (_Float16*)alloc((size_t)chunk * 512 * 2);
  _Float16* H_h  = (_Float16*)alloc((size_t)chunk * 1024 * 2);
  _Float16* H_l  = (_Float16*)alloc((size_t)chunk * 1024 * 2);
  float* pMa  = (float*)alloc((size_t)32 * chunk * 4);
  float* pM2a = (float*)alloc((size_t)32 * chunk * 4);
  float* pSa  = (float*)alloc((size_t)32 * chunk * 4);
  int*   pIa  = (int*)alloc((size_t)32 * chunk * 4);
  _Float16* y1_h = xs_h;   // alias: xs consumed by gemm1 before ln_dual writes
  _Float16* y1_l = xs_l;

  zero_cnt<<<2, 256, 0, stream>>>(cnt);
  prep_wvo_split<<<1024, 256, 0, stream>>>(vw, ow, wvo_h, wvo_l);
  prep_cvec<<<2, 256, 0, stream>>>(ow, vb, ob, cvec);
  prep_w1p_split<<<2048, 256, 0, stream>>>(w1, lng, w1p_h, w1p_l);
  prep_b1p<<<4, 256, 0, stream>>>(w1, lnb, b1, b1p);
  prep_w2_split<<<8192, 256, 0, stream>>>(w2, w2_h, w2_l);

  int citer = 0;
  for (int row0 = 0; row0 < MTOT; row0 += chunk, ++citer) {
    int rows = (MTOT - row0 < chunk) ? (MTOT - row0) : chunk;
    split_x<<<rows * 512 / 2048, 256, 0, stream>>>(X + (size_t)row0 * 512, xs_h, xs_l);
    gemm_split<0, 512, 512><<<dim3(rows / 128, 4), 256, 0, stream>>>(
        xs_h, xs_l, wvo_h, wvo_l, cvec, Abuf, nullptr, nullptr,
        nullptr, nullptr, nullptr, 0);
    ln_dual<<<rows / 4, 256, 0, stream>>>(Abuf, X + (size_t)row0 * 512, na,
                                          y0_h, y0_l, y1_h, y1_l);
    for (int s = 0; s < 2; ++s) {
      int* cp = cnt + citer * 2 + s;
      gemm_split<1, 512, 1024><<<dim3(rows / 128, 8), 256, 0, stream>>>(
          s == 0 ? y0_h : y1_h, s == 0 ? y0_l : y1_l, w1p_h, w1p_l, b1p,
          nullptr, H_h, H_l, nullptr, nullptr, nullptr, 0);
      gemm_approx<<<dim3(8, rows / 256), 512, 0, stream>>>(
          H_h, w2_h, b2, pMa, pM2a, pSa, pIa, chunk);
      flag_k<<<(rows + 255) / 256, 256, 0, stream>>>(
          pMa, pM2a, pSa, pIa, chunk, rows,
          s == 0 ? map0 : map1, s == 0 ? iap0 : iap1, row0, list, cp);
      gather_k<<<CAPR, 128, 0, stream>>>(H_h, H_l, list, cp, Gh, Gl);
      gemm_split<2, 1024, 2048><<<dim3(32, 16), 256, 0, stream>>>(
          Gh, Gl, w2_h, w2_l, b2, nullptr, nullptr, nullptr,
          pMr, pIr, cp, CAPR);
      rescue_merge<<<CAPR / 256, 256, 0, stream>>>(
          pMr, pIr, list, cp, s == 0 ? iap0 : iap1, row0);
    }
  }
  finalize_k<<<MTOT / 256, 256, 0, stream>>>(map0, iap0, map1, iap1, out);
}

// Round 4
// 1587.991 us; speedup vs baseline: 2.4634x; 2.4634x over previous
//
#include <hip/hip_runtime.h>
#include <math.h>

#define MTOT 32768   // B*R
#define DD   512
#define HHD  1024
#define NRELN 2048
#define SCA  64.f          // activation fp16 pre-scale
#define SCB  1024.f        // weight fp16 pre-scale
#define INVS (1.f / 65536.f)
#define CAPR 4096          // rescue row capacity (expected ~1300/step)
#define MARGIN 2.0e-3f     // approx-gap rescue threshold (~50 sigma of approx err)

typedef _Float16 h8  __attribute__((ext_vector_type(8)));
typedef float    f4  __attribute__((ext_vector_type(4)));
typedef float    f16v __attribute__((ext_vector_type(16)));

__device__ __forceinline__ void fsplit(float x, _Float16& h, _Float16& l) {
  _Float16 t = (_Float16)x;
  h = t;
  l = (_Float16)(x - (float)t);   // hi/lo split: 2^-22 rel error total
}

__device__ __forceinline__ void gld16(const _Float16* g, _Float16* l) {
  __builtin_amdgcn_global_load_lds(
      (const __attribute__((address_space(1))) void*)g,
      (__attribute__((address_space(3))) void*)l, 16, 0, 0);
}

// ---------------- prep: fold + scale + split weights ----------------

__global__ void prep_wvo_split(const float* __restrict__ vw, const float* __restrict__ ow,
                               _Float16* __restrict__ wh, _Float16* __restrict__ wl) {
  int idx = blockIdx.x * 256 + threadIdx.x;   // 512*512
  int k = idx & 511;
  int n = idx >> 9;
  float s = 0.f;
  for (int j = 0; j < DD; ++j) s += ow[n * DD + j] * vw[j * DD + k];
  fsplit(s * SCB, wh[n * DD + k], wl[n * DD + k]);
}

__global__ void prep_cvec(const float* __restrict__ ow, const float* __restrict__ vb,
                          const float* __restrict__ ob, float* __restrict__ c) {
  int i = blockIdx.x * 256 + threadIdx.x;
  if (i < DD) {
    float s = ob[i];
    for (int k = 0; k < DD; ++k) s += ow[i * DD + k] * vb[k];
    c[i] = s;
  }
}

__global__ void prep_w1p_split(const float* __restrict__ w1, const float* __restrict__ g,
                               _Float16* __restrict__ wh, _Float16* __restrict__ wl) {
  int idx = blockIdx.x * 256 + threadIdx.x;   // 1024*512
  int k = idx & 511;
  int n = idx >> 9;
  fsplit(w1[n * DD + k] * g[k] * SCB, wh[n * DD + k], wl[n * DD + k]);
}

__global__ void prep_b1p(const float* __restrict__ w1, const float* __restrict__ lnb,
                         const float* __restrict__ b1, float* __restrict__ b1p) {
  int n = blockIdx.x * 256 + threadIdx.x;
  if (n < HHD) {
    float s = b1[n];
    for (int k = 0; k < DD; ++k) s += w1[n * DD + k] * lnb[k];
    b1p[n] = s;
  }
}

__global__ void prep_w2_split(const float* __restrict__ w2,
                              _Float16* __restrict__ wh, _Float16* __restrict__ wl) {
  int idx = blockIdx.x * 256 + threadIdx.x;   // 2048*1024
  int k = idx & 1023;
  int n = idx >> 10;
  fsplit(w2[n * HHD + k] * SCB, wh[n * HHD + k], wl[n * HHD + k]);
}

__global__ void split_x(const float* __restrict__ src, _Float16* __restrict__ h,
                        _Float16* __restrict__ l) {
  int idx = (blockIdx.x * 256 + threadIdx.x) * 8;
  float4 a = *(const float4*)(src + idx);
  float4 b = *(const float4*)(src + idx + 4);
  float vv[8] = {a.x, a.y, a.z, a.w, b.x, b.y, b.z, b.w};
  _Float16 hh[8], ll[8];
#pragma unroll
  for (int i = 0; i < 8; ++i) fsplit(vv[i] * SCA, hh[i], ll[i]);
  *(h8*)(h + idx) = *(h8*)hh;
  *(h8*)(l + idx) = *(h8*)ll;
}

__global__ void zero_cnt(int* c) { c[blockIdx.x * 256 + threadIdx.x] = 0; }

// ---------------- exact fp16-split GEMM (3-product), 128x128, BK=32 ----------
// SW(r) = ((r>>1)^(r>>3))&3 chunk swizzle.
// MODE 0: +bias -> fp32 out. MODE 1: +bias, relu, *SCA, split -> H.
// MODE 2: rescue rows (count from *cntp, grid-stride): per-row (max, argmax)
//         -> pM/pI partials (32 col-slots), stride pstr.
template <int MODE, int KDIM, int NTOT>
__global__ __launch_bounds__(256) void gemm_split(
    const _Float16* __restrict__ Ah, const _Float16* __restrict__ Al,
    const _Float16* __restrict__ Bh, const _Float16* __restrict__ Bl,
    const float* __restrict__ bias,
    float* __restrict__ outF,
    _Float16* __restrict__ outHh, _Float16* __restrict__ outHl,
    float* __restrict__ pM, float* __restrict__ pI,
    const int* __restrict__ cntp, int pstr) {
  __shared__ __align__(16) _Float16 sA[2][128][32];
  __shared__ __align__(16) _Float16 sB[2][128][32];
  const int t = threadIdx.x;
  const int lane = t & 63;
  const int wv = t >> 6;
  const int wr = wv & 1, wc = wv >> 1;
  const int l31 = lane & 31, half = lane >> 5;
  const int n0 = blockIdx.y << 7;

  const _Float16* gsp = (wv == 0) ? Ah : (wv == 1) ? Al : (wv == 2) ? Bh : Bl;
  _Float16* lbase = (wv == 0) ? &sA[0][0][0] : (wv == 1) ? &sA[1][0][0]
                  : (wv == 2) ? &sB[0][0][0] : &sB[1][0][0];
  const int srow = lane >> 2;
  const int scp = lane & 3;
  const int swzE = ((srow >> 1) & 3) ^ ((srow >> 3) & 1);
  const int swzO = swzE ^ 2;
  const int swz = ((l31 >> 1) ^ (l31 >> 3)) & 3;   // frag-read side

  int nmb;
  if constexpr (MODE == 2) {
    int a = *cntp;
    if (a > CAPR) a = CAPR;
    nmb = (a + 127) >> 7;
  } else {
    nmb = gridDim.x;
  }

  for (int mb = blockIdx.x; mb < nmb; mb += gridDim.x) {
    const int m0 = mb << 7;
    const int gb = (wv < 2) ? m0 : n0;
    const _Float16* gA0 = gsp + (size_t)(gb + srow) * KDIM + ((scp ^ swzE) << 3);
    const _Float16* gA1 = gsp + (size_t)(gb + srow) * KDIM + ((scp ^ swzO) << 3);

    f16v acc[2][2] = {};
    for (int k0 = 0; k0 < KDIM; k0 += 32) {
      __syncthreads();
#pragma unroll
      for (int it = 0; it < 8; ++it)
        gld16(((it & 1) ? gA1 : gA0) + (size_t)(it * 16) * KDIM + k0, lbase + it * 512);
      __syncthreads();
#pragma unroll
      for (int ks = 0; ks < 2; ++ks) {
        const int pos = (((ks << 1) + half) ^ swz) << 3;
        h8 af_h[2], af_l[2], bf_h[2], bf_l[2];
#pragma unroll
        for (int i = 0; i < 2; ++i) {
          const int mr = wr * 64 + i * 32 + l31;
          af_h[i] = *(const h8*)&sA[0][mr][pos];
          af_l[i] = *(const h8*)&sA[1][mr][pos];
        }
#pragma unroll
        for (int j = 0; j < 2; ++j) {
          const int nr = wc * 64 + j * 32 + l31;
          bf_h[j] = *(const h8*)&sB[0][nr][pos];
          bf_l[j] = *(const h8*)&sB[1][nr][pos];
        }
#pragma unroll
        for (int j = 0; j < 2; ++j)
#pragma unroll
          for (int i = 0; i < 2; ++i) {
            acc[i][j] = __builtin_amdgcn_mfma_f32_32x32x16_f16(af_h[i], bf_h[j], acc[i][j], 0, 0, 0);
            acc[i][j] = __builtin_amdgcn_mfma_f32_32x32x16_f16(af_h[i], bf_l[j], acc[i][j], 0, 0, 0);
            acc[i][j] = __builtin_amdgcn_mfma_f32_32x32x16_f16(af_l[i], bf_h[j], acc[i][j], 0, 0, 0);
          }
      }
    }

    // C/D (32x32): col = lane&31, row = (r&3)+8*(r>>2)+4*half
    float bb[2];
    int gc[2];
#pragma unroll
    for (int j = 0; j < 2; ++j) {
      gc[j] = n0 + wc * 64 + j * 32 + l31;
      bb[j] = bias[gc[j]];
    }
    if constexpr (MODE == 0) {
#pragma unroll
      for (int i = 0; i < 2; ++i)
#pragma unroll
        for (int r = 0; r < 16; ++r) {
          const int row = m0 + wr * 64 + i * 32 + (r & 3) + 8 * (r >> 2) + 4 * half;
#pragma unroll
          for (int j = 0; j < 2; ++j)
            outF[(size_t)row * NTOT + gc[j]] = acc[i][j][r] * INVS + bb[j];
        }
    } else if constexpr (MODE == 1) {
#pragma unroll
      for (int i = 0; i < 2; ++i)
#pragma unroll
        for (int r = 0; r < 16; ++r) {
          const int row = m0 + wr * 64 + i * 32 + (r & 3) + 8 * (r >> 2) + 4 * half;
#pragma unroll
          for (int j = 0; j < 2; ++j) {
            float v = fmaxf(acc[i][j][r] * INVS + bb[j], 0.f) * SCA;
            _Float16 hh, ll;
            fsplit(v, hh, ll);
            outHh[(size_t)row * NTOT + gc[j]] = hh;
            outHl[(size_t)row * NTOT + gc[j]] = ll;
          }
        }
    } else {
      const int slot = blockIdx.y * 2 + wc;   // 32 col-slots of 64
#pragma unroll
      for (int i = 0; i < 2; ++i)
#pragma unroll
        for (int r = 0; r < 16; ++r) {
          float v0 = acc[i][0][r] * INVS + bb[0];
          float v1 = acc[i][1][r] * INVS + bb[1];
          float M;
          int I;
          if (v0 >= v1) { M = v0; I = gc[0]; }
          else          { M = v1; I = gc[1]; }
#pragma unroll
          for (int sh = 1; sh <= 16; sh <<= 1) {
            float M2 = __shfl_xor(M, sh);
            int   I2 = __shfl_xor(I, sh);
            if (M2 > M || (M2 == M && I2 < I)) { M = M2; I = I2; }
          }
          if (l31 == 0) {
            const int grow = m0 + wr * 64 + i * 32 + (r & 3) + 8 * (r >> 2) + 4 * half;
            pM[(size_t)slot * pstr + grow] = M;
            pI[(size_t)slot * pstr + grow] = (float)I;
          }
        }
    }
  }
}

// ---------------- approx GEMM (hh only): 128x128, 32x32x16, 4 blocks/CU -----
// Round-4 redesign around the register/occupancy constraint discovered in
// rounds 0-3: every prior config ran ~2 waves/SIMD (round-0: 68 VGPR + 64
// AGPR = 132; rounds 1-2: 240; round-3's forced cap spilled 2.3 GB to
// scratch). All sat at MfmaUtil 21-22% with NO pipe saturated -> latency-
// bound from insufficient independent waves. This kernel fits the 128-reg
// class for real: per-wave 64x64 out via 2x2 frags of mfma_f32_32x32x16_f16
// -> acc = 64 AGPR exactly; live VGPR ~55 (4 frags + 8 ds offsets + staging).
// 4 waves/block, 32 KiB LDS single-buffer -> 4 blocks/CU resident, 16
// waves/CU, 4 independent barrier groups: block A's stage-drain overlaps
// block B's MFMA burst (m114). Grid 2048 blocks = 8/CU of queued work.
// Per K-tile (BK=64): sync -> 8x gld16 -> sync (vmcnt(0) drain) -> 16 MFMA.
// XCD decode kept (groups of 128 ids = 8 m-strips x 16 n-tiles -> A-panel
// sharers on one XCD; FETCH stays ~80 MB). XOR chunk swizzle (c ^= row&7)
// via pre-swizzled global source, bank-balanced b128 reads.
// Accumulation order differs from rounds 0-3 (32x32x16 vs 16x16x32) -- safe:
// argmax within MARGIN goes to the exact rescue path; the 0.1 threshold on
// 1/S has ~200x slack.
// Epilogue: per-row online (max, 2nd-max, first-argmax, sumexp), 32-lane
// half reduce (C/D 32x32: col=l31, row=(r&3)+8*(r>>2)+4*half), 32 col-slots
// of 64 (slot = nb*2 + wc), stride astr -- flag_k unchanged.

__global__ __launch_bounds__(256, 4) void gemm_approx(
    const _Float16* __restrict__ Ah, const _Float16* __restrict__ Bh,
    const float* __restrict__ bias,
    float* __restrict__ pM, float* __restrict__ pM2,
    float* __restrict__ pS, int* __restrict__ pI, int astr) {
  __shared__ __align__(16) _Float16 lds[16384];   // A[128][64] | B[128][64]
  const int t = threadIdx.x;
  const int lane = t & 63;
  const int wv = t >> 6;        // 0..3
  const int wr = wv >> 1;       // m half: rows wr*64..+63
  const int wc = wv & 1;        // n half: cols wc*64..+63
  const int l31 = lane & 31, half = lane >> 5;

  // ---- XCD-aware (mb, nb) decode: groups of 128 ids = 8 strips x 16 nb ----
  const int Tm = gridDim.y >> 1;               // #m-strips = rows/128
  const int id = blockIdx.x + (blockIdx.y << 3);
  const int g8 = (id >> 7) << 3;
  const int r0 = id & 127;
  int mb, nb;
  if (g8 + 8 <= Tm) { mb = g8 + (r0 & 7); nb = r0 >> 3; }
  else { int rem = Tm - g8; mb = g8 + (r0 % rem); nb = r0 / rem; }
  const int m0 = mb << 7;
  const int n0 = nb << 7;

  // staging: issue i in 0..3 per matrix; thread -> row i*32+(t>>3), chunk t&7
  const int srow = t >> 3;
  const int schk = (t & 7) ^ (srow & 7);       // inverse-swizzled source chunk
  const int sAb = (m0 + srow) * HHD + schk * 8;   // half offsets
  const int sBb = (n0 + srow) * HHD + schk * 8;
  _Float16* dA = lds + t * 8;                  // + i*2048 halfs per issue
  _Float16* dB = lds + 8192 + t * 8;

  // frag-read ds offsets (halfs): row base + swizzled k-chunk per k-step
  int aks[4], bks[4];
#pragma unroll
  for (int ks = 0; ks < 4; ++ks) {
    int chk = ((ks << 1) + half) ^ (l31 & 7);
    aks[ks] = (wr * 64 + l31) * 64 + chk * 8;
    bks[ks] = 8192 + (wc * 64 + l31) * 64 + chk * 8;
  }

  f16v acc[2][2] = {};

  for (int kt = 0; kt < 16; ++kt) {
    __syncthreads();   // all waves done reading the buffer (no-op at kt=0)
#pragma unroll
    for (int i = 0; i < 4; ++i) {
      gld16(Ah + (size_t)(sAb + i * 32 * HHD + kt * 64), dA + i * 2048);
      gld16(Bh + (size_t)(sBb + i * 32 * HHD + kt * 64), dB + i * 2048);
    }
    __syncthreads();   // vmcnt(0) drain + barrier: tile loads landed
    __builtin_amdgcn_s_setprio(1);
#pragma unroll
    for (int ks = 0; ks < 4; ++ks) {
      h8 af0 = *(const h8*)(lds + aks[ks]);
      h8 af1 = *(const h8*)(lds + aks[ks] + 2048);
      h8 bf0 = *(const h8*)(lds + bks[ks]);
      h8 bf1 = *(const h8*)(lds + bks[ks] + 2048);
      acc[0][0] = __builtin_amdgcn_mfma_f32_32x32x16_f16(af0, bf0, acc[0][0], 0, 0, 0);
      acc[0][1] = __builtin_amdgcn_mfma_f32_32x32x16_f16(af0, bf1, acc[0][1], 0, 0, 0);
      acc[1][0] = __builtin_amdgcn_mfma_f32_32x32x16_f16(af1, bf0, acc[1][0], 0, 0, 0);
      acc[1][1] = __builtin_amdgcn_mfma_f32_32x32x16_f16(af1, bf1, acc[1][1], 0, 0, 0);
    }
    __builtin_amdgcn_s_setprio(0);
  }

  // epilogue; C/D 32x32: col = l31, row = (r&3)+8*(r>>2)+4*half
  const int slot = nb * 2 + wc;   // 32 slots of 64 cols
  float bb[2];
  int gcx[2];
#pragma unroll
  for (int j = 0; j < 2; ++j) {
    gcx[j] = n0 + wc * 64 + j * 32 + l31;
    bb[j] = bias[gcx[j]];
  }
#pragma unroll
  for (int i = 0; i < 2; ++i)
#pragma unroll
    for (int rr = 0; rr < 16; ++rr) {
      float M = acc[i][0][rr] * INVS + bb[0], M2 = -INFINITY, S = 1.f;
      int I = gcx[0];
      {
        float v = acc[i][1][rr] * INVS + bb[1];
        if (v > M) { S = S * __expf(M - v) + 1.f; M2 = M; M = v; I = gcx[1]; }
        else       { S += __expf(v - M); M2 = fmaxf(M2, v); }
      }
#pragma unroll
      for (int sh = 1; sh <= 16; sh <<= 1) {   // reduce across the 32-lane half
        float Mo = __shfl_xor(M, sh);
        float M2o = __shfl_xor(M2, sh);
        float So = __shfl_xor(S, sh);
        int   Io = __shfl_xor(I, sh);
        if (Mo > M || (Mo == M && Io < I)) {
          S = S * __expf(M - Mo) + So; M2 = fmaxf(M, M2o); M = Mo; I = Io;
        } else {
          S += So * __expf(Mo - M); M2 = fmaxf(M2, Mo);
        }
      }
      if (l31 == 0) {
        const int grow = m0 + wr * 64 + i * 32 + (rr & 3) + 8 * (rr >> 2) + 4 * half;
        pM[(size_t)slot * astr + grow] = M;
        pM2[(size_t)slot * astr + grow] = M2;
        pS[(size_t)slot * astr + grow] = S;
        pI[(size_t)slot * astr + grow] = I;
      }
    }
}

// -------- flag: merge 32 approx slots; emit m/i; flag small gaps ----
__global__ void flag_k(const float* __restrict__ pM, const float* __restrict__ pM2,
                       const float* __restrict__ pS, const int* __restrict__ pI,
                       int astr, int rows,
                       float* __restrict__ map, int* __restrict__ iap, int row0,
                       int* __restrict__ list, int* __restrict__ cnt) {
  int r = blockIdx.x * 256 + threadIdx.x;
  if (r >= rows) return;
  float M = pM[r], M2 = pM2[r], S = pS[r];
  int I = pI[r];
  for (int s = 1; s < 32; ++s) {
    size_t o = (size_t)s * astr + r;
    float m = pM[o], m2 = pM2[o], ss = pS[o];
    int ii = pI[o];
    if (m > M || (m == M && ii < I)) {
      M2 = fmaxf(M, m2); S = S * __expf(M - m) + ss; M = m; I = ii;
    } else {
      M2 = fmaxf(M2, m); S += ss * __expf(m - M);
    }
  }
  map[row0 + r] = 1.f / S;
  iap[row0 + r] = I;
  if (M - M2 < MARGIN) {
    int c = atomicAdd(cnt, 1);
    if (c < CAPR) list[c] = r;   // chunk-local row
  }
}

// -------- gather flagged H rows (exact split) into dense rescue buffer ------
__global__ void gather_k(const _Float16* __restrict__ Hh, const _Float16* __restrict__ Hl,
                         const int* __restrict__ list, const int* __restrict__ cnt,
                         _Float16* __restrict__ Gh, _Float16* __restrict__ Gl) {
  int b = blockIdx.x;
  int active = *cnt;
  if (active > CAPR) active = CAPR;
  if (b >= active) return;
  int r = list[b];
  int t = threadIdx.x;   // 128 threads x 8 halfs = 1024
  *(h8*)(Gh + (size_t)b * HHD + t * 8) = *(const h8*)(Hh + (size_t)r * HHD + t * 8);
  *(h8*)(Gl + (size_t)b * HHD + t * 8) = *(const h8*)(Hl + (size_t)r * HHD + t * 8);
}

// -------- rescue merge: exact argmax over 32 slots -> overwrite iap ---------
__global__ void rescue_merge(const float* __restrict__ pMr, const float* __restrict__ pIr,
                             const int* __restrict__ list, const int* __restrict__ cnt,
                             int* __restrict__ iap, int row0) {
  int c = blockIdx.x * 256 + threadIdx.x;
  int a = *cnt;
  if (a > CAPR) a = CAPR;
  if (c >= a) return;
  float M = pMr[c];
  int I = (int)pIr[c];
  for (int s = 1; s < 32; ++s) {
    size_t o = (size_t)s * CAPR + c;
    float m = pMr[o];
    int i2 = (int)pIr[o];
    if (m > M || (m == M && i2 < I)) { M = m; I = i2; }
  }
  iap[row0 + list[c]] = I;
}

// ------- ln_dual: one pass over A+X -> both step activations, split --------
__global__ __launch_bounds__(256) void ln_dual(
    const float* __restrict__ A, const float* __restrict__ X,
    const float* __restrict__ na,
    _Float16* __restrict__ y0h, _Float16* __restrict__ y0l,
    _Float16* __restrict__ y1h, _Float16* __restrict__ y1l) {
  int t = threadIdx.x;
  int lane = t & 63;
  int w = t >> 6;
  int r = blockIdx.x * 4 + w;
  const float* ap = A + (size_t)r * DD + lane * 8;
  const float* xp = X + (size_t)r * DD + lane * 8;
  const float* np = na + lane * 8;
  float v0[8], v1[8];
  float s0 = 0.f, q0 = 0.f, s1 = 0.f, q1 = 0.f;
#pragma unroll
  for (int i = 0; i < 8; ++i) {
    float a = ap[i];
    v0[i] = a + np[i];
    v1[i] = a + xp[i];
    s0 += v0[i]; q0 += v0[i] * v0[i];
    s1 += v1[i]; q1 += v1[i] * v1[i];
  }
#pragma unroll
  for (int m = 1; m <= 32; m <<= 1) {
    s0 += __shfl_xor(s0, m); q0 += __shfl_xor(q0, m);
    s1 += __shfl_xor(s1, m); q1 += __shfl_xor(q1, m);
  }
  float mu0 = s0 * (1.f / DD), mu1 = s1 * (1.f / DD);
  float rs0 = 1.f / sqrtf(q0 * (1.f / DD) - mu0 * mu0 + 1e-5f);
  float rs1 = 1.f / sqrtf(q1 * (1.f / DD) - mu1 * mu1 + 1e-5f);
  _Float16 h0[8], l0[8], h1[8], l1[8];
#pragma unroll
  for (int i = 0; i < 8; ++i) {
    fsplit((v0[i] - mu0) * rs0 * SCA, h0[i], l0[i]);
    fsplit((v1[i] - mu1) * rs1 * SCA, h1[i], l1[i]);
  }
  *(h8*)(y0h + (size_t)r * DD + lane * 8) = *(h8*)h0;
  *(h8*)(y0l + (size_t)r * DD + lane * 8) = *(h8*)l0;
  *(h8*)(y1h + (size_t)r * DD + lane * 8) = *(h8*)h1;
  *(h8*)(y1l + (size_t)r * DD + lane * 8) = *(h8*)l1;
}

// ---------------- finalize ----------------
__global__ void finalize_k(const float* __restrict__ map0, const int* __restrict__ iap0,
                           const float* __restrict__ map1, const int* __restrict__ iap1,
                           float* __restrict__ out) {
  int r = blockIdx.x * 256 + threadIdx.x;
  float m0v = map0[r], m1v = map1[r];
  int i0v = iap0[r], i1v = iap1[r];
  bool c0 = (i0v != 0) && (m0v >= 0.1f);
  bool c1 = c0 && (i1v != 0) && (m1v >= 0.1f);
  out[r] = c0 ? (c1 ? m0v * m1v : m0v) : 0.f;
  out[MTOT + r] = (float)i0v;
  out[2 * MTOT + r] = (float)i1v;
  out[3 * MTOT + r] = (float)((c0 ? 1 : 0) + (c1 ? 1 : 0));
}

// ---------------- host ----------------
extern "C" void kernel_launch(void* const* d_in, const int* in_sizes, int n_in,
                              void* d_out, int out_size, void* d_ws, size_t ws_size,
                              hipStream_t stream) {
  const float* X   = (const float*)d_in[0];
  const float* na  = (const float*)d_in[1];
  const float* vw  = (const float*)d_in[2];
  const float* vb  = (const float*)d_in[3];
  const float* ow  = (const float*)d_in[4];
  const float* ob  = (const float*)d_in[5];
  const float* lng = (const float*)d_in[6];
  const float* lnb = (const float*)d_in[7];
  const float* w1  = (const float*)d_in[8];
  const float* b1  = (const float*)d_in[9];
  const float* w2  = (const float*)d_in[10];
  const float* b2  = (const float*)d_in[11];
  float* out = (float*)d_out;

  char* p = (char*)d_ws;
  auto alloc = [&](size_t bytes) -> void* {
    void* r = (void*)p;
    p += (bytes + 255) & ~(size_t)255;
    return r;
  };
  // ---- fixed allocations (~30 MB) ----
  _Float16* wvo_h = (_Float16*)alloc(512 * 512 * 2);
  _Float16* wvo_l = (_Float16*)alloc(512 * 512 * 2);
  float*    cvec  = (float*)alloc(512 * 4);
  _Float16* w1p_h = (_Float16*)alloc(1024 * 512 * 2);
  _Float16* w1p_l = (_Float16*)alloc(1024 * 512 * 2);
  float*    b1p   = (float*)alloc(1024 * 4);
  _Float16* w2_h  = (_Float16*)alloc(2048 * 1024 * 2);
  _Float16* w2_l  = (_Float16*)alloc(2048 * 1024 * 2);
  float* map0 = (float*)alloc((size_t)MTOT * 4);
  float* map1 = (float*)alloc((size_t)MTOT * 4);
  int* iap0 = (int*)alloc((size_t)MTOT * 4);
  int* iap1 = (int*)alloc((size_t)MTOT * 4);
  int* list = (int*)alloc(CAPR * 4);
  int* cnt  = (int*)alloc(512 * 4);   // per-(chunk,step) counters
  float* pMr = (float*)alloc((size_t)32 * CAPR * 4);
  float* pIr = (float*)alloc((size_t)32 * CAPR * 4);
  _Float16* Gh = (_Float16*)alloc((size_t)CAPR * HHD * 2);
  _Float16* Gl = (_Float16*)alloc((size_t)CAPR * HHD * 2);

  // ---- chunk sizing: per-row bytes = xs 2048 + A 2048 + y0 2048 + H 4096
  //      + approx partials (32 slots x 16 B) 512 = 10752 ----
  size_t fixed = (size_t)(p - (char*)d_ws);
  size_t reserve = 2u << 20;
  size_t remain = ws_size > fixed + reserve ? ws_size - fixed - reserve : 0;
  int chunk = (int)(remain / 10752);
  chunk &= ~255;                       // keep rows multiple of 256
  if (chunk < 256) chunk = 256;
  if (chunk > MTOT) chunk = MTOT;

  _Float16* xs_h = (_Float16*)alloc((size_t)chunk * 512 * 2);
  _Float16* xs_l = (_Float16*)alloc((size_t)chunk * 512 * 2);
  float*    Abuf = (float*)alloc((size_t)chunk * 512 * 4);
  _Float16* y0_h = (_Float16*)alloc((size_t)chunk * 512 * 2);
  _Float16* y0_l = (_Float16*)alloc((size_t)chunk * 512 * 2);
  _Float16* H_h  = (_Float16*)alloc((size_t)chunk * 1024 * 2);
  _Float16* H_l  = (_Float16*)alloc((size_t)chunk * 1024 * 2);
  float* pMa  = (float*)alloc((size_t)32 * chunk * 4);
  float* pM2a = (float*)alloc((size_t)32 * chunk * 4);
  float* pSa  = (float*)alloc((size_t)32 * chunk * 4);
  int*   pIa  = (int*)alloc((size_t)32 * chunk * 4);
  _Float16* y1_h = xs_h;   // alias: xs consumed by gemm1 before ln_dual writes
  _Float16* y1_l = xs_l;

  zero_cnt<<<2, 256, 0, stream>>>(cnt);
  prep_wvo_split<<<1024, 256, 0, stream>>>(vw, ow, wvo_h, wvo_l);
  prep_cvec<<<2, 256, 0, stream>>>(ow, vb, ob, cvec);
  prep_w1p_split<<<2048, 256, 0, stream>>>(w1, lng, w1p_h, w1p_l);
  prep_b1p<<<4, 256, 0, stream>>>(w1, lnb, b1, b1p);
  prep_w2_split<<<8192, 256, 0, stream>>>(w2, w2_h, w2_l);

  int citer = 0;
  for (int row0 = 0; row0 < MTOT; row0 += chunk, ++citer) {
    int rows = (MTOT - row0 < chunk) ? (MTOT - row0) : chunk;
    split_x<<<rows * 512 / 2048, 256, 0, stream>>>(X + (size_t)row0 * 512, xs_h, xs_l);
    gemm_split<0, 512, 512><<<dim3(rows / 128, 4), 256, 0, stream>>>(
        xs_h, xs_l, wvo_h, wvo_l, cvec, Abuf, nullptr, nullptr,
        nullptr, nullptr, nullptr, 0);
    ln_dual<<<rows / 4, 256, 0, stream>>>(Abuf, X + (size_t)row0 * 512, na,
                                          y0_h, y0_l, y1_h, y1_l);
    for (int s = 0; s < 2; ++s) {
      int* cp = cnt + citer * 2 + s;
      gemm_split<1, 512, 1024><<<dim3(rows / 128, 8), 256, 0, stream>>>(
          s == 0 ? y0_h : y1_h, s == 0 ? y0_l : y1_l, w1p_h, w1p_l, b1p,
          nullptr, H_h, H_l, nullptr, nullptr, nullptr, 0);
      gemm_approx<<<dim3(8, rows / 64), 256, 0, stream>>>(
          H_h, w2_h, b2, pMa, pM2a, pSa, pIa, chunk);
      flag_k<<<(rows + 255) / 256, 256, 0, stream>>>(
          pMa, pM2a, pSa, pIa, chunk, rows,
          s == 0 ? map0 : map1, s == 0 ? iap0 : iap1, row0, list, cp);
      gather_k<<<CAPR, 128, 0, stream>>>(H_h, H_l, list, cp, Gh, Gl);
      gemm_split<2, 1024, 2048><<<dim3(32, 16), 256, 0, stream>>>(
          Gh, Gl, w2_h, w2_l, b2, nullptr, nullptr, nullptr,
          pMr, pIr, cp, CAPR);
      rescue_merge<<<CAPR / 256, 256, 0, stream>>>(
          pMr, pIr, list, cp, s == 0 ? iap0 : iap1, row0);
    }
  }
  finalize_k<<<MTOT / 256, 256, 0, stream>>>(map0, iap0, map1, iap1, out);
}